// Round 9
// baseline (2169.274 us; speedup 1.0000x reference)
//
#include <hip/hip_runtime.h>
#include <hip/hip_bf16.h>
#include <stdint.h>

#define D 64
typedef __hip_bfloat16 bf16;
typedef unsigned short u16;

__device__ __forceinline__ float bf2f(u16 u) { return __uint_as_float(((uint32_t)u) << 16); }
__device__ __forceinline__ float lo16(uint32_t w) { return __uint_as_float(w << 16); }
__device__ __forceinline__ float hi16(uint32_t w) { return __uint_as_float(w & 0xffff0000u); }

template <bool F32>
__device__ __forceinline__ float ld(const void* p, int i) {
    if constexpr (F32) return ((const float*)p)[i];
    else return bf2f(((const u16*)p)[i]);
}

// ---- dtype oracle (proven) ----
__global__ __launch_bounds__(256) void detect_kernel(const void* x, const int* ei, int* flags) {
    __shared__ float smax[256];
    __shared__ int sor[256];
    int t = threadIdx.x;
    const u16* xs = (const u16*)x;
    float mx = 0.f;
#pragma unroll
    for (int i = 0; i < 16; ++i) {
        float a = fabsf(bf2f(xs[t * 16 + i]));
        if (!(a == a)) a = 1e30f;
        mx = fmaxf(mx, a);
    }
    int any = 0;
#pragma unroll
    for (int i = 0; i < 8; ++i) any |= ei[2 * (t * 8 + i) + 1];
    smax[t] = mx; sor[t] = any;
    __syncthreads();
    for (int s = 128; s > 0; s >>= 1) {
        if (t < s) { smax[t] = fmaxf(smax[t], smax[t + s]); sor[t] |= sor[t + s]; }
        __syncthreads();
    }
    if (t == 0) { flags[0] = (smax[0] > 1000.f) ? 1 : 0; flags[1] = (sor[0] != 0) ? 1 : 0; }
}

// ---- node_transform (proven) ----
template <bool F32>
__device__ __forceinline__ void nt_body(const void* x, const void* Wnt, const void* bnt,
                                        float* h, int N) {
    int gid = blockIdx.x * 256 + threadIdx.x;
    if (gid >= N * D) return;
    int n = gid >> 6, c = gid & 63;
    float acc = ld<F32>(bnt, c);
#pragma unroll
    for (int k = 0; k < 6; ++k)
        acc = fmaf(ld<F32>(x, n * 6 + k), ld<F32>(Wnt, c * 6 + k), acc);
    h[gid] = fmaxf(acc, 0.f);
}
__global__ __launch_bounds__(256) void nt_kernel(const int* flags, const void* x, const void* Wnt,
                                                 const void* bnt, float* h, int N) {
    if (flags[0]) nt_body<true>(x, Wnt, bnt, h, N);
    else          nt_body<false>(x, Wnt, bnt, h, N);
}

// ---- weight transpose for gates (round-8 verified) ----
__global__ __launch_bounds__(256) void wtrans_kernel(const uint32_t* __restrict__ Wih,
                                                     const uint32_t* __restrict__ Whh,
                                                     uint32_t* __restrict__ WT2) {
    int i = blockIdx.x * 256 + threadIdx.x;
    if (i >= 12288) return;
    int mat = i / 6144, rem = i % 6144;
    int kk = rem / 192, r = rem % 192;
    const uint32_t* src = mat ? Whh : Wih;
    WT2[i] = src[r * 32 + kk];
}

// ================= CSR build (dst-major), once per call =================
__global__ __launch_bounds__(256) void hist_kernel(const int* __restrict__ flags,
                                                   const int* __restrict__ ei,
                                                   int* __restrict__ cnt, int E, int N) {
    int i = blockIdx.x * 256 + threadIdx.x;
    if (i >= E) return;
    int dst = flags[1] ? ei[E + i] : ei[2 * (E + i)];
    if ((unsigned)dst < (unsigned)N) atomicAdd(&cnt[dst], 1);
}

__global__ __launch_bounds__(256) void scan1_kernel(const int* __restrict__ cnt,
                                                    int* __restrict__ bsum, int N) {
    __shared__ int sm[256];
    int t = threadIdx.x, i = blockIdx.x * 256 + t;
    sm[t] = (i < N) ? cnt[i] : 0;
    __syncthreads();
    for (int s = 128; s > 0; s >>= 1) {
        if (t < s) sm[t] += sm[t + s];
        __syncthreads();
    }
    if (t == 0) bsum[blockIdx.x] = sm[0];
}

__global__ __launch_bounds__(256) void scan2_kernel(const int* __restrict__ bsum,
                                                    int* __restrict__ boff,
                                                    int* __restrict__ rs, int NB, int N) {
    __shared__ int sm[256];
    int t = threadIdx.x;
    int v = (t < NB) ? bsum[t] : 0;
    sm[t] = v;
    __syncthreads();
    for (int off = 1; off < 256; off <<= 1) {
        int u = (t >= off) ? sm[t - off] : 0;
        __syncthreads();
        sm[t] += u;
        __syncthreads();
    }
    boff[t] = sm[t] - v;            // exclusive
    if (t == 255) rs[N] = sm[255];  // total valid edges
}

__global__ __launch_bounds__(256) void scan3_kernel(const int* __restrict__ cnt,
                                                    const int* __restrict__ boff,
                                                    int* __restrict__ rs, int N) {
    __shared__ int sm[256];
    int t = threadIdx.x, i = blockIdx.x * 256 + t;
    int v = (i < N) ? cnt[i] : 0;
    sm[t] = v;
    __syncthreads();
    for (int off = 1; off < 256; off <<= 1) {
        int u = (t >= off) ? sm[t - off] : 0;
        __syncthreads();
        sm[t] += u;
        __syncthreads();
    }
    if (i < N) rs[i] = boff[blockIdx.x] + sm[t] - v;
}

__global__ __launch_bounds__(256) void fill_kernel(const int* __restrict__ flags,
                                                   const int* __restrict__ ei,
                                                   const int* __restrict__ rs,
                                                   int* __restrict__ cur,
                                                   int* __restrict__ ss, int E, int N) {
    int i = blockIdx.x * 256 + threadIdx.x;
    if (i >= E) return;
    int src, dst;
    if (flags[1]) { src = ei[i];     dst = ei[E + i]; }
    else          { src = ei[2 * i]; dst = ei[2 * (E + i)]; }
    if ((unsigned)src >= (unsigned)N || (unsigned)dst >= (unsigned)N) return;
    int pos = atomicAdd(&cur[dst], 1);
    ss[rs[dst] + pos] = src;
}

// ================= bf16 fused layer: gather(h) -> @W -> GRU =================
// Block = 256 threads = 16 nodes; lane = channel; wave handles 4 nodes.
__global__ __launch_bounds__(256) void layer_bf16(const int* __restrict__ flags,
                                                  const float* __restrict__ hcur,
                                                  const int* __restrict__ rs,
                                                  const int* __restrict__ ss,
                                                  const u16* __restrict__ W, int woff,
                                                  const uint32_t* __restrict__ WT2,
                                                  const u16* __restrict__ bih,
                                                  const u16* __restrict__ bhh,
                                                  float* __restrict__ hout,
                                                  bf16* __restrict__ obf, int N) {
    if (flags[0]) return;  // f32 world handled by shadow kernels
    __shared__ float LA[16 * 66];  // gathered sum of h[src]
    __shared__ float LH[16 * 66];  // own h rows
    __shared__ float LM[16 * 66];  // (sum h) @ W
    __shared__ float LB[384];
    int t = threadIdx.x;
    int n0 = blockIdx.x * 16;
    int lane = t & 63;
    int w4 = (t >> 6) * 4;

    {   // stage own h rows (coalesced float4) + biases
        int row = t >> 4, col = (t & 15) * 4;
        bool v = (n0 + row) < N;
        float4 vh = v ? *(const float4*)(hcur + (size_t)(n0 + row) * D + col)
                      : make_float4(0.f, 0.f, 0.f, 0.f);
        LH[row * 66 + col + 0] = vh.x; LH[row * 66 + col + 1] = vh.y;
        LH[row * 66 + col + 2] = vh.z; LH[row * 66 + col + 3] = vh.w;
        if (t < 192) { LB[t] = bf2f(bih[t]); LB[192 + t] = bf2f(bhh[t]); }
    }
    // gather: each wave sums incoming h rows for its 4 nodes; lane = channel
#pragma unroll 1
    for (int nn = 0; nn < 4; ++nn) {
        int n = n0 + w4 + nn;  // wave-uniform
        float acc = 0.f;
        if (n < N) {
            int s = rs[n], e2 = rs[n + 1];
            int j = s;
            for (; j + 3 < e2; j += 4) {  // 4-way pipelined (independent loads)
                int s0 = ss[j], s1 = ss[j + 1], s2 = ss[j + 2], s3 = ss[j + 3];
                float a0 = hcur[(size_t)s0 * D + lane];
                float a1 = hcur[(size_t)s1 * D + lane];
                float a2 = hcur[(size_t)s2 * D + lane];
                float a3 = hcur[(size_t)s3 * D + lane];
                acc += (a0 + a1) + (a2 + a3);
            }
            for (; j < e2; ++j) acc += hcur[(size_t)ss[j] * D + lane];
        }
        LA[(w4 + nn) * 66 + lane] = acc;
    }
    __syncthreads();
    {   // matvec: LM[nn][c] = sum_k LA[nn][k] * W[k][c]   (W bf16, L1-hot 8 KB)
        const u16* Wl = W + woff;
        float mv[4] = {0.f, 0.f, 0.f, 0.f};
#pragma unroll 4
        for (int k = 0; k < 64; ++k) {
            float wv = bf2f(Wl[k * 64 + lane]);
#pragma unroll
            for (int nn = 0; nn < 4; ++nn)
                mv[nn] = fmaf(LA[(w4 + nn) * 66 + k], wv, mv[nn]);
        }
#pragma unroll
        for (int nn = 0; nn < 4; ++nn) LM[(w4 + nn) * 66 + lane] = mv[nn];
    }
    __syncthreads();
    // gates (round-8-verified code, source = LM/LH)
    const uint32_t* WT = WT2;
    const uint32_t* VT = WT2 + 6144;
    float br = LB[lane] + LB[192 + lane];
    float bz = LB[64 + lane] + LB[256 + lane];
    float bi = LB[128 + lane];
    float bh = LB[320 + lane];
    float ra[4], za[4], ia[4], ha[4];
#pragma unroll
    for (int nn = 0; nn < 4; ++nn) { ra[nn] = br; za[nn] = bz; ia[nn] = bi; ha[nn] = bh; }
#pragma unroll 2
    for (int kk = 0; kk < 32; ++kk) {
        uint32_t w0 = WT[kk * 192 + lane];
        uint32_t w1 = WT[kk * 192 + 64 + lane];
        uint32_t w2 = WT[kk * 192 + 128 + lane];
        uint32_t v0 = VT[kk * 192 + lane];
        uint32_t v1 = VT[kk * 192 + 64 + lane];
        uint32_t v2 = VT[kk * 192 + 128 + lane];
        float w0l = lo16(w0), w0h = hi16(w0), w1l = lo16(w1), w1h = hi16(w1);
        float w2l = lo16(w2), w2h = hi16(w2), v0l = lo16(v0), v0h = hi16(v0);
        float v1l = lo16(v1), v1h = hi16(v1), v2l = lo16(v2), v2h = hi16(v2);
#pragma unroll
        for (int nn = 0; nn < 4; ++nn) {
            int rr = w4 + nn;
            float2 a = *(const float2*)&LM[rr * 66 + 2 * kk];
            float2 hh = *(const float2*)&LH[rr * 66 + 2 * kk];
            ra[nn] = fmaf(a.x, w0l, fmaf(a.y, w0h, ra[nn]));
            za[nn] = fmaf(a.x, w1l, fmaf(a.y, w1h, za[nn]));
            ia[nn] = fmaf(a.x, w2l, fmaf(a.y, w2h, ia[nn]));
            ra[nn] = fmaf(hh.x, v0l, fmaf(hh.y, v0h, ra[nn]));
            za[nn] = fmaf(hh.x, v1l, fmaf(hh.y, v1h, za[nn]));
            ha[nn] = fmaf(hh.x, v2l, fmaf(hh.y, v2h, ha[nn]));
        }
    }
#pragma unroll
    for (int nn = 0; nn < 4; ++nn) {
        int n = n0 + w4 + nn;
        float r = 1.f / (1.f + __expf(-ra[nn]));
        float z = 1.f / (1.f + __expf(-za[nn]));
        float nx = ia[nn] + r * ha[nn];
        float tnh = 1.f - 2.f / (1.f + __expf(2.f * nx));  // tanh, overflow-safe
        float hn = (1.f - z) * tnh + z * LH[(w4 + nn) * 66 + lane];
        if (n < N) {
            if (obf) obf[(size_t)n * D + lane] = __float2bfloat16(hn);
            else     hout[(size_t)n * D + lane] = hn;
        }
    }
}

// ================= f32-world shadow pipeline (guarded; proven bodies) =================
__global__ __launch_bounds__(256) void zero_f32(const int* flags, float* agg, int ND) {
    if (!flags[0]) return;
    int i = blockIdx.x * 256 + threadIdx.x;
    if (i < ND) agg[i] = 0.f;
}
__global__ __launch_bounds__(256) void m_f32(const int* flags, const float* h, const void* W,
                                             int woff, float* m, int N) {
    if (!flags[0]) return;
    int lane = threadIdx.x & 63;
    int n = blockIdx.x * 4 + (threadIdx.x >> 6);
    if (n >= N) return;
    const float* hrow = h + (size_t)n * D;
    float acc = 0.f;
#pragma unroll
    for (int k = 0; k < D; ++k)
        acc = fmaf(hrow[k], ld<true>(W, woff + k * D + lane), acc);
    m[(size_t)n * D + lane] = acc;
}
__global__ __launch_bounds__(256) void scatter_f32(const int* flags, const float* __restrict__ m,
                                                   const int* __restrict__ ei,
                                                   float* __restrict__ agg, int E, int N) {
    if (!flags[0]) return;
    int e = blockIdx.x * 4 + (threadIdx.x >> 6);
    if (e >= E) return;
    int lane = threadIdx.x & 63;
    int src, dst;
    if (flags[1]) { src = ei[e];     dst = ei[E + e]; }
    else          { src = ei[2 * e]; dst = ei[2 * (E + e)]; }
    if ((unsigned)src >= (unsigned)N || (unsigned)dst >= (unsigned)N) return;
    atomicAdd(&agg[(size_t)dst * D + lane], m[(size_t)src * D + lane]);
}
__global__ __launch_bounds__(256, 1) void gru_f32(const int* flags, const float* agg, const float* h,
                                                  const void* Wih, const void* Whh,
                                                  const void* bih, const void* bhh,
                                                  float* hout, int N) {
    if (!flags[0]) return;
    int lane = threadIdx.x & 63;
    int sub = threadIdx.x >> 6;
    int n = blockIdx.x * 64 + lane;
    if (n >= N) return;
    float ar[D], hv[D];
    const float4* a4 = (const float4*)(agg + (size_t)n * D);
    const float4* h4 = (const float4*)(h + (size_t)n * D);
#pragma unroll
    for (int i = 0; i < 16; ++i) {
        float4 v = a4[i];
        ar[4 * i] = v.x; ar[4 * i + 1] = v.y; ar[4 * i + 2] = v.z; ar[4 * i + 3] = v.w;
        float4 w = h4[i];
        hv[4 * i] = w.x; hv[4 * i + 1] = w.y; hv[4 * i + 2] = w.z; hv[4 * i + 3] = w.w;
    }
    int c0 = sub * 16;
#pragma unroll 1
    for (int cc = 0; cc < 16; ++cc) {
        int c = c0 + cc;
        float air = ld<true>(bih, c), aiz = ld<true>(bih, 64 + c), ain = ld<true>(bih, 128 + c);
        float ahr = ld<true>(bhh, c), ahz = ld<true>(bhh, 64 + c), ahn = ld<true>(bhh, 128 + c);
#pragma unroll
        for (int k = 0; k < D; ++k) {
            air = fmaf(ar[k], ld<true>(Wih, c * D + k), air);
            aiz = fmaf(ar[k], ld<true>(Wih, (64 + c) * D + k), aiz);
            ain = fmaf(ar[k], ld<true>(Wih, (128 + c) * D + k), ain);
            ahr = fmaf(hv[k], ld<true>(Whh, c * D + k), ahr);
            ahz = fmaf(hv[k], ld<true>(Whh, (64 + c) * D + k), ahz);
            ahn = fmaf(hv[k], ld<true>(Whh, (128 + c) * D + k), ahn);
        }
        float r = 1.f / (1.f + __expf(-(air + ahr)));
        float z = 1.f / (1.f + __expf(-(aiz + ahz)));
        float nx = ain + r * ahn;
        float nn = 1.f - 2.f / (1.f + __expf(2.f * nx));
        float hcur = h[(size_t)n * D + c];
        hout[(size_t)n * D + c] = (1.f - z) * nn + z * hcur;
    }
}
// f32 world writes fp32 straight to d_out on last layer
__global__ __launch_bounds__(256) void copy_f32_out(const int* flags, const float* h,
                                                    float* out, int ND) {
    if (!flags[0]) return;
    int i = blockIdx.x * 256 + threadIdx.x;
    if (i < ND) out[i] = h[i];
}

extern "C" void kernel_launch(void* const* d_in, const int* in_sizes, int n_in,
                              void* d_out, int out_size, void* d_ws, size_t ws_size,
                              hipStream_t stream) {
    const void* x   = d_in[0];
    const int*  ei  = (const int*)d_in[1];
    const void* Wnt = d_in[4];
    const void* bnt = d_in[5];
    const void* Wt  = d_in[6];   // [3,64,64]
    const void* Wih = d_in[7];
    const void* Whh = d_in[8];
    const void* bih = d_in[9];
    const void* bhh = d_in[10];

    int N = in_sizes[0] / 6;
    int E = in_sizes[1] / 2;
    int ND = N * D;
    int NB = (N + 255) / 256;

    // Workspace (within proven 38.4 MB + 48 KB footprint):
    // flags | hA | hB | X ; X holds CSR+WT2 (bf16 world) or agg (f32 world) — exclusive.
    int* flags = (int*)d_ws;
    float* hA = (float*)((char*)d_ws + 256);
    float* hB = hA + ND;
    char* X = (char*)(hB + ND);
    int* rs   = (int*)X;               // N+1
    int* cnt  = rs + (N + 1);          // N
    int* bsum = cnt + N;               // 256
    int* boff = bsum + 256;            // 256
    int* ss   = boff + 256;            // E
    uint32_t* WT2 = (uint32_t*)(ss + E);  // 12288 dwords
    float* agg = (float*)X;            // f32-world alias

    detect_kernel<<<1, 256, 0, stream>>>(x, ei, flags);
    nt_kernel<<<(ND + 255) / 256, 256, 0, stream>>>(flags, x, Wnt, bnt, hA, N);
    wtrans_kernel<<<48, 256, 0, stream>>>((const uint32_t*)Wih, (const uint32_t*)Whh, WT2);

    // CSR build (bf16 world uses it; harmless in f32 world)
    hipMemsetAsync(cnt, 0, (size_t)N * sizeof(int), stream);
    hist_kernel<<<(E + 255) / 256, 256, 0, stream>>>(flags, ei, cnt, E, N);
    scan1_kernel<<<NB, 256, 0, stream>>>(cnt, bsum, N);
    scan2_kernel<<<1, 256, 0, stream>>>(bsum, boff, rs, NB, N);
    scan3_kernel<<<NB, 256, 0, stream>>>(cnt, boff, rs, N);
    hipMemsetAsync(cnt, 0, (size_t)N * sizeof(int), stream);
    fill_kernel<<<(E + 255) / 256, 256, 0, stream>>>(flags, ei, rs, cnt, ss, E, N);

    float* hcur = hA;
    float* hnxt = hB;
    for (int layer = 0; layer < 3; ++layer) {
        bool last = (layer == 2);
        // f32 shadow (no-ops in bf16 world)
        zero_f32<<<(ND + 255) / 256, 256, 0, stream>>>(flags, agg, ND);
        m_f32<<<(N + 3) / 4, 256, 0, stream>>>(flags, hcur, Wt, layer * D * D, hnxt, N);
        scatter_f32<<<(E + 3) / 4, 256, 0, stream>>>(flags, hnxt, ei, agg, E, N);
        gru_f32<<<(N + 63) / 64, 256, 0, stream>>>(flags, agg, hcur, Wih, Whh, bih, bhh, hnxt, N);
        if (last) copy_f32_out<<<(ND + 255) / 256, 256, 0, stream>>>(flags, hnxt, (float*)d_out, ND);
        // bf16 fused layer (no-op in f32 world)
        layer_bf16<<<(N + 15) / 16, 256, 0, stream>>>(flags, hcur, rs, ss,
                                                      (const u16*)Wt, layer * D * D, WT2,
                                                      (const u16*)bih, (const u16*)bhh,
                                                      last ? nullptr : hnxt,
                                                      last ? (bf16*)d_out : nullptr, N);
        float* t = hcur; hcur = hnxt; hnxt = t;
    }
}

// Round 10
// 533.468 us; speedup vs baseline: 4.0664x; 4.0664x over previous
//
#include <hip/hip_runtime.h>
#include <hip/hip_bf16.h>
#include <stdint.h>

#define D 64
typedef __hip_bfloat16 bf16;
typedef unsigned short u16;

__device__ __forceinline__ float bf2f(u16 u) { return __uint_as_float(((uint32_t)u) << 16); }

template <bool F32>
__device__ __forceinline__ float ld(const void* p, int i) {
    if constexpr (F32) return ((const float*)p)[i];
    else return bf2f(((const u16*)p)[i]);
}

// ---- dtype oracle (proven): flags[0]=1 -> fp32 floats; flags[1]=1 -> int32 idx ----
__global__ __launch_bounds__(256) void detect_kernel(const void* x, const int* ei, int* flags) {
    __shared__ float smax[256];
    __shared__ int sor[256];
    int t = threadIdx.x;
    const u16* xs = (const u16*)x;
    float mx = 0.f;
#pragma unroll
    for (int i = 0; i < 16; ++i) {
        float a = fabsf(bf2f(xs[t * 16 + i]));
        if (!(a == a)) a = 1e30f;
        mx = fmaxf(mx, a);
    }
    int any = 0;
#pragma unroll
    for (int i = 0; i < 8; ++i) any |= ei[2 * (t * 8 + i) + 1];
    smax[t] = mx; sor[t] = any;
    __syncthreads();
    for (int s = 128; s > 0; s >>= 1) {
        if (t < s) { smax[t] = fmaxf(smax[t], smax[t + s]); sor[t] |= sor[t + s]; }
        __syncthreads();
    }
    if (t == 0) { flags[0] = (smax[0] > 1000.f) ? 1 : 0; flags[1] = (sor[0] != 0) ? 1 : 0; }
}

// ---- node_transform (proven) ----
template <bool F32>
__device__ __forceinline__ void nt_body(const void* x, const void* Wnt, const void* bnt,
                                        float* h, int N) {
    int gid = blockIdx.x * 256 + threadIdx.x;
    if (gid >= N * D) return;
    int n = gid >> 6, c = gid & 63;
    float acc = ld<F32>(bnt, c);
#pragma unroll
    for (int k = 0; k < 6; ++k)
        acc = fmaf(ld<F32>(x, n * 6 + k), ld<F32>(Wnt, c * 6 + k), acc);
    h[gid] = fmaxf(acc, 0.f);
}
__global__ __launch_bounds__(256) void nt_kernel(const int* flags, const void* x, const void* Wnt,
                                                 const void* bnt, float* h, int N) {
    if (flags[0]) nt_body<true>(x, Wnt, bnt, h, N);
    else          nt_body<false>(x, Wnt, bnt, h, N);
}

// ---- fp32 gate-weight transpose: WT[m][k*192 + r] = src[r*64 + k] (f32 world only) ----
__global__ __launch_bounds__(256) void wtrans_f32(const int* __restrict__ flags,
                                                  const float* __restrict__ Wih,
                                                  const float* __restrict__ Whh,
                                                  float* __restrict__ WT) {
    if (!flags[0]) return;
    int i = blockIdx.x * 256 + threadIdx.x;
    if (i >= 24576) return;
    int m = i / 12288, rem = i % 12288;
    int k = rem / 192, r = rem % 192;
    const float* s = m ? Whh : Wih;
    WT[i] = s[r * 64 + k];
}

// ================= CSR build (dst-major), once per call =================
__global__ __launch_bounds__(256) void hist_kernel(const int* __restrict__ flags,
                                                   const int* __restrict__ ei,
                                                   int* __restrict__ cnt, int E, int N) {
    int i = blockIdx.x * 256 + threadIdx.x;
    if (i >= E) return;
    int dst = flags[1] ? ei[E + i] : ei[2 * (E + i)];
    if ((unsigned)dst < (unsigned)N) atomicAdd(&cnt[dst], 1);
}
__global__ __launch_bounds__(256) void scan1_kernel(const int* __restrict__ cnt,
                                                    int* __restrict__ bsum, int N) {
    __shared__ int sm[256];
    int t = threadIdx.x, i = blockIdx.x * 256 + t;
    sm[t] = (i < N) ? cnt[i] : 0;
    __syncthreads();
    for (int s = 128; s > 0; s >>= 1) {
        if (t < s) sm[t] += sm[t + s];
        __syncthreads();
    }
    if (t == 0) bsum[blockIdx.x] = sm[0];
}
__global__ __launch_bounds__(256) void scan2_kernel(const int* __restrict__ bsum,
                                                    int* __restrict__ boff,
                                                    int* __restrict__ rs, int NB, int N) {
    __shared__ int sm[256];
    int t = threadIdx.x;
    int v = (t < NB) ? bsum[t] : 0;
    sm[t] = v;
    __syncthreads();
    for (int off = 1; off < 256; off <<= 1) {
        int u = (t >= off) ? sm[t - off] : 0;
        __syncthreads();
        sm[t] += u;
        __syncthreads();
    }
    boff[t] = sm[t] - v;
    if (t == 255) rs[N] = sm[255];
}
__global__ __launch_bounds__(256) void scan3_kernel(const int* __restrict__ cnt,
                                                    const int* __restrict__ boff,
                                                    int* __restrict__ rs, int N) {
    __shared__ int sm[256];
    int t = threadIdx.x, i = blockIdx.x * 256 + t;
    int v = (i < N) ? cnt[i] : 0;
    sm[t] = v;
    __syncthreads();
    for (int off = 1; off < 256; off <<= 1) {
        int u = (t >= off) ? sm[t - off] : 0;
        __syncthreads();
        sm[t] += u;
        __syncthreads();
    }
    if (i < N) rs[i] = boff[blockIdx.x] + sm[t] - v;
}
__global__ __launch_bounds__(256) void fill_kernel(const int* __restrict__ flags,
                                                   const int* __restrict__ ei,
                                                   const int* __restrict__ rs,
                                                   int* __restrict__ cur,
                                                   int* __restrict__ ss, int E, int N) {
    int i = blockIdx.x * 256 + threadIdx.x;
    if (i >= E) return;
    int src, dst;
    if (flags[1]) { src = ei[i];     dst = ei[E + i]; }
    else          { src = ei[2 * i]; dst = ei[2 * (E + i)]; }
    if ((unsigned)src >= (unsigned)N || (unsigned)dst >= (unsigned)N) return;
    int pos = atomicAdd(&cur[dst], 1);
    ss[rs[dst] + pos] = src;
}

// ======= fp32 fused layer: gather-sum(h[src]) -> @W -> GRU gates =======
// Block = 256 threads = 16 nodes; lane = channel; each wave owns 4 nodes.
__global__ __launch_bounds__(256) void layer_f32(const int* __restrict__ flags,
                                                 const float* __restrict__ hcur,
                                                 const int* __restrict__ rs,
                                                 const int* __restrict__ ss,
                                                 const float* __restrict__ W,   // layer slice [64,64]
                                                 const float* __restrict__ WT,  // gates k-major [2][64][192]
                                                 const float* __restrict__ bih,
                                                 const float* __restrict__ bhh,
                                                 float* __restrict__ outp, int N) {
    if (!flags[0]) return;
    __shared__ float LH[16 * 66];
    __shared__ float LA[16 * 66];
    __shared__ float LM[16 * 66];
    __shared__ float LB[384];
    int t = threadIdx.x;
    int n0 = blockIdx.x * 16;
    int lane = t & 63;
    int w4 = (t >> 6) * 4;

    {   // stage own h rows (coalesced float4) + biases
        int row = t >> 4, col = (t & 15) * 4;
        bool v = (n0 + row) < N;
        float4 vh = v ? *(const float4*)(hcur + (size_t)(n0 + row) * D + col)
                      : make_float4(0.f, 0.f, 0.f, 0.f);
        LH[row * 66 + col + 0] = vh.x; LH[row * 66 + col + 1] = vh.y;
        LH[row * 66 + col + 2] = vh.z; LH[row * 66 + col + 3] = vh.w;
        if (t < 192) { LB[t] = bih[t]; LB[192 + t] = bhh[t]; }
    }
    __syncthreads();

    // gather: sum of incoming h rows per node (coalesced 256B row reads, 8-way MLP)
#pragma unroll 1
    for (int nn = 0; nn < 4; ++nn) {
        int n = n0 + w4 + nn;  // wave-uniform
        float acc = 0.f;
        if (n < N) {
            int s = rs[n], e2 = rs[n + 1];
            int j = s;
            for (; j + 7 < e2; j += 8) {
                int i0 = ss[j], i1 = ss[j + 1], i2 = ss[j + 2], i3 = ss[j + 3];
                int i4 = ss[j + 4], i5 = ss[j + 5], i6 = ss[j + 6], i7 = ss[j + 7];
                float a0 = hcur[(size_t)i0 * D + lane];
                float a1 = hcur[(size_t)i1 * D + lane];
                float a2 = hcur[(size_t)i2 * D + lane];
                float a3 = hcur[(size_t)i3 * D + lane];
                float a4 = hcur[(size_t)i4 * D + lane];
                float a5 = hcur[(size_t)i5 * D + lane];
                float a6 = hcur[(size_t)i6 * D + lane];
                float a7 = hcur[(size_t)i7 * D + lane];
                acc += ((a0 + a1) + (a2 + a3)) + ((a4 + a5) + (a6 + a7));
            }
            for (; j < e2; ++j) acc += hcur[(size_t)ss[j] * D + lane];
        }
        LA[(w4 + nn) * 66 + lane] = acc;
    }
    __syncthreads();

    {   // matvec: LM[nn][c] = sum_k LA[nn][k] * W[k][c]  (W 16 KB, L1-hot)
        float mv[4] = {0.f, 0.f, 0.f, 0.f};
#pragma unroll 4
        for (int k = 0; k < 64; ++k) {
            float wv = W[k * 64 + lane];
#pragma unroll
            for (int nn = 0; nn < 4; ++nn)
                mv[nn] = fmaf(LA[(w4 + nn) * 66 + k], wv, mv[nn]);
        }
#pragma unroll
        for (int nn = 0; nn < 4; ++nn) LM[(w4 + nn) * 66 + lane] = mv[nn];
    }
    __syncthreads();

    // gates: lane = channel c; WT rows k-major [k][gate*64+c]
    const float* WTi = WT;
    const float* WTh = WT + 12288;
    float br = LB[lane] + LB[192 + lane];
    float bz = LB[64 + lane] + LB[256 + lane];
    float bi = LB[128 + lane];
    float bh = LB[320 + lane];
    float ra[4], za[4], ia[4], ha[4];
#pragma unroll
    for (int nn = 0; nn < 4; ++nn) { ra[nn] = br; za[nn] = bz; ia[nn] = bi; ha[nn] = bh; }
#pragma unroll 4
    for (int k = 0; k < 64; ++k) {
        float w0 = WTi[k * 192 + lane];
        float w1 = WTi[k * 192 + 64 + lane];
        float w2 = WTi[k * 192 + 128 + lane];
        float v0 = WTh[k * 192 + lane];
        float v1 = WTh[k * 192 + 64 + lane];
        float v2 = WTh[k * 192 + 128 + lane];
#pragma unroll
        for (int nn = 0; nn < 4; ++nn) {
            int rr = w4 + nn;
            float a = LM[rr * 66 + k];
            float hh = LH[rr * 66 + k];
            ra[nn] = fmaf(a, w0, fmaf(hh, v0, ra[nn]));
            za[nn] = fmaf(a, w1, fmaf(hh, v1, za[nn]));
            ia[nn] = fmaf(a, w2, ia[nn]);
            ha[nn] = fmaf(hh, v2, ha[nn]);
        }
    }
#pragma unroll
    for (int nn = 0; nn < 4; ++nn) {
        int n = n0 + w4 + nn;
        float r = 1.f / (1.f + __expf(-ra[nn]));
        float z = 1.f / (1.f + __expf(-za[nn]));
        float nx = ia[nn] + r * ha[nn];
        float tnh = 1.f - 2.f / (1.f + __expf(2.f * nx));  // tanh, overflow-safe
        float hn = (1.f - z) * tnh + z * LH[(w4 + nn) * 66 + lane];
        if (n < N) outp[(size_t)n * D + lane] = hn;
    }
}

// ======= bf16-world shadow pipeline (grid-stride, proven round-6 bodies; never runs here) =======
__global__ __launch_bounds__(256) void zero_sh(const int* flags, float* agg, int ND) {
    if (flags[0]) return;
    for (int i = blockIdx.x * 256 + threadIdx.x; i < ND; i += 256 * 1024) agg[i] = 0.f;
}
__global__ __launch_bounds__(256) void m_sh(const int* flags, const float* h, const u16* W,
                                            int woff, float* m, int N) {
    if (flags[0]) return;
    int lane = threadIdx.x & 63;
    for (int n = blockIdx.x * 4 + (threadIdx.x >> 6); n < N; n += 4 * 1024) {
        const float* hrow = h + (size_t)n * D;
        float acc = 0.f;
#pragma unroll
        for (int k = 0; k < D; ++k)
            acc = fmaf(hrow[k], bf2f(W[woff + k * D + lane]), acc);
        m[(size_t)n * D + lane] = acc;
    }
}
__global__ __launch_bounds__(256) void scatter_sh(const int* flags, const float* __restrict__ m,
                                                  const int* __restrict__ ei,
                                                  float* __restrict__ agg, int E, int N) {
    if (flags[0]) return;
    int lane = threadIdx.x & 63;
    for (int e = blockIdx.x * 4 + (threadIdx.x >> 6); e < E; e += 4 * 2048) {
        int src, dst;
        if (flags[1]) { src = ei[e];     dst = ei[E + e]; }
        else          { src = ei[2 * e]; dst = ei[2 * (E + e)]; }
        if ((unsigned)src >= (unsigned)N || (unsigned)dst >= (unsigned)N) continue;
        atomicAdd(&agg[(size_t)dst * D + lane], m[(size_t)src * D + lane]);
    }
}
__global__ __launch_bounds__(256, 1) void gru_sh(const int* flags, const float* agg, const float* h,
                                                 const u16* Wih, const u16* Whh,
                                                 const u16* bih, const u16* bhh,
                                                 float* hout, bf16* obf, int N) {
    if (flags[0]) return;
    int lane = threadIdx.x & 63;
    int sub = threadIdx.x >> 6;
    for (int n = blockIdx.x * 64 + lane; n < N; n += 64 * 1024) {
        float ar[D], hv[D];
        const float4* a4 = (const float4*)(agg + (size_t)n * D);
        const float4* h4 = (const float4*)(h + (size_t)n * D);
#pragma unroll
        for (int i = 0; i < 16; ++i) {
            float4 v = a4[i];
            ar[4 * i] = v.x; ar[4 * i + 1] = v.y; ar[4 * i + 2] = v.z; ar[4 * i + 3] = v.w;
            float4 w = h4[i];
            hv[4 * i] = w.x; hv[4 * i + 1] = w.y; hv[4 * i + 2] = w.z; hv[4 * i + 3] = w.w;
        }
        int c0 = sub * 16;
#pragma unroll 1
        for (int cc = 0; cc < 16; ++cc) {
            int c = c0 + cc;
            float air = bf2f(bih[c]), aiz = bf2f(bih[64 + c]), ain = bf2f(bih[128 + c]);
            float ahr = bf2f(bhh[c]), ahz = bf2f(bhh[64 + c]), ahn = bf2f(bhh[128 + c]);
#pragma unroll
            for (int k = 0; k < D; ++k) {
                air = fmaf(ar[k], bf2f(Wih[c * D + k]), air);
                aiz = fmaf(ar[k], bf2f(Wih[(64 + c) * D + k]), aiz);
                ain = fmaf(ar[k], bf2f(Wih[(128 + c) * D + k]), ain);
                ahr = fmaf(hv[k], bf2f(Whh[c * D + k]), ahr);
                ahz = fmaf(hv[k], bf2f(Whh[(64 + c) * D + k]), ahz);
                ahn = fmaf(hv[k], bf2f(Whh[(128 + c) * D + k]), ahn);
            }
            float r = 1.f / (1.f + __expf(-(air + ahr)));
            float z = 1.f / (1.f + __expf(-(aiz + ahz)));
            float nx = ain + r * ahn;
            float nn = 1.f - 2.f / (1.f + __expf(2.f * nx));
            float hcur = h[(size_t)n * D + c];
            float hn = (1.f - z) * nn + z * hcur;
            if (hout) hout[(size_t)n * D + c] = hn;
            else obf[(size_t)n * D + c] = __float2bfloat16(hn);
        }
    }
}

extern "C" void kernel_launch(void* const* d_in, const int* in_sizes, int n_in,
                              void* d_out, int out_size, void* d_ws, size_t ws_size,
                              hipStream_t stream) {
    const void* x   = d_in[0];
    const int*  ei  = (const int*)d_in[1];
    const void* Wnt = d_in[4];
    const void* bnt = d_in[5];
    const void* Wt  = d_in[6];   // [3,64,64]
    const void* Wih = d_in[7];   // [192,64]
    const void* Whh = d_in[8];
    const void* bih = d_in[9];
    const void* bhh = d_in[10];

    int N = in_sizes[0] / 6;
    int E = in_sizes[1] / 2;
    int ND = N * D;
    int NB = (N + 255) / 256;

    // Workspace (proven 38.4 MB footprint): flags | hA | hB | C
    // C = CSR(rs,cnt,bsum,boff,ss)+WT (f32 world)  OR  agg (bf16 shadow world)
    int* flags = (int*)d_ws;
    float* hA = (float*)((char*)d_ws + 256);
    float* hB = hA + ND;
    char* C = (char*)(hB + ND);
    int* rs   = (int*)C;                 // N+1
    int* cnt  = rs + (N + 1);            // N
    int* bsum = cnt + N;                 // 256
    int* boff = bsum + 256;              // 256
    int* ss   = boff + 256;              // E
    float* WT = (float*)(ss + E);        // 24576 floats (96 KB)
    float* aggsh = (float*)C;            // bf16-shadow alias

    detect_kernel<<<1, 256, 0, stream>>>(x, ei, flags);
    nt_kernel<<<(ND + 255) / 256, 256, 0, stream>>>(flags, x, Wnt, bnt, hA, N);
    wtrans_f32<<<96, 256, 0, stream>>>(flags, (const float*)Wih, (const float*)Whh, WT);

    // CSR build (consumed in f32 world; harmlessly clobbered in shadow world)
    hipMemsetAsync(cnt, 0, (size_t)N * sizeof(int), stream);
    hist_kernel<<<(E + 255) / 256, 256, 0, stream>>>(flags, ei, cnt, E, N);
    scan1_kernel<<<NB, 256, 0, stream>>>(cnt, bsum, N);
    scan2_kernel<<<1, 256, 0, stream>>>(bsum, boff, rs, NB, N);
    scan3_kernel<<<NB, 256, 0, stream>>>(cnt, boff, rs, N);
    hipMemsetAsync(cnt, 0, (size_t)N * sizeof(int), stream);
    fill_kernel<<<(E + 255) / 256, 256, 0, stream>>>(flags, ei, rs, cnt, ss, E, N);

    float* hcur = hA;
    float* hnxt = hB;
    for (int layer = 0; layer < 3; ++layer) {
        bool last = (layer == 2);
        // bf16-world shadow (no-ops in f32 world); m aliases hnxt, round-6 pattern
        zero_sh<<<1024, 256, 0, stream>>>(flags, aggsh, ND);
        m_sh<<<1024, 256, 0, stream>>>(flags, hcur, (const u16*)Wt, layer * D * D, hnxt, N);
        scatter_sh<<<2048, 256, 0, stream>>>(flags, hnxt, ei, aggsh, E, N);
        gru_sh<<<1024, 256, 0, stream>>>(flags, aggsh, hcur,
                                         (const u16*)Wih, (const u16*)Whh,
                                         (const u16*)bih, (const u16*)bhh,
                                         last ? nullptr : hnxt,
                                         last ? (bf16*)d_out : nullptr, N);
        // f32 fused layer (the real path)
        layer_f32<<<(N + 15) / 16, 256, 0, stream>>>(flags, hcur, rs, ss,
                                                     (const float*)Wt + layer * D * D, WT,
                                                     (const float*)bih, (const float*)bhh,
                                                     last ? (float*)d_out : hnxt, N);
        float* t = hcur; hcur = hnxt; hnxt = t;
    }
}

// Round 11
// 513.960 us; speedup vs baseline: 4.2207x; 1.0380x over previous
//
#include <hip/hip_runtime.h>
#include <hip/hip_bf16.h>
#include <stdint.h>

#define D 64
typedef __hip_bfloat16 bf16;
typedef unsigned short u16;

__device__ __forceinline__ float bf2f(u16 u) { return __uint_as_float(((uint32_t)u) << 16); }

template <bool F32>
__device__ __forceinline__ float ld(const void* p, int i) {
    if constexpr (F32) return ((const float*)p)[i];
    else return bf2f(((const u16*)p)[i]);
}

// ---- dtype oracle (proven): flags[0]=1 -> fp32 floats; flags[1]=1 -> int32 idx ----
__global__ __launch_bounds__(256) void detect_kernel(const void* x, const int* ei, int* flags) {
    __shared__ float smax[256];
    __shared__ int sor[256];
    int t = threadIdx.x;
    const u16* xs = (const u16*)x;
    float mx = 0.f;
#pragma unroll
    for (int i = 0; i < 16; ++i) {
        float a = fabsf(bf2f(xs[t * 16 + i]));
        if (!(a == a)) a = 1e30f;
        mx = fmaxf(mx, a);
    }
    int any = 0;
#pragma unroll
    for (int i = 0; i < 8; ++i) any |= ei[2 * (t * 8 + i) + 1];
    smax[t] = mx; sor[t] = any;
    __syncthreads();
    for (int s = 128; s > 0; s >>= 1) {
        if (t < s) { smax[t] = fmaxf(smax[t], smax[t + s]); sor[t] |= sor[t + s]; }
        __syncthreads();
    }
    if (t == 0) { flags[0] = (smax[0] > 1000.f) ? 1 : 0; flags[1] = (sor[0] != 0) ? 1 : 0; }
}

// ---- node_transform (proven) ----
template <bool F32>
__device__ __forceinline__ void nt_body(const void* x, const void* Wnt, const void* bnt,
                                        float* h, int N) {
    int gid = blockIdx.x * 256 + threadIdx.x;
    if (gid >= N * D) return;
    int n = gid >> 6, c = gid & 63;
    float acc = ld<F32>(bnt, c);
#pragma unroll
    for (int k = 0; k < 6; ++k)
        acc = fmaf(ld<F32>(x, n * 6 + k), ld<F32>(Wnt, c * 6 + k), acc);
    h[gid] = fmaxf(acc, 0.f);
}
__global__ __launch_bounds__(256) void nt_kernel(const int* flags, const void* x, const void* Wnt,
                                                 const void* bnt, float* h, int N) {
    if (flags[0]) nt_body<true>(x, Wnt, bnt, h, N);
    else          nt_body<false>(x, Wnt, bnt, h, N);
}

// ---- prep: combined weights, all fp32 outputs.
//  WCT[l][k*192 + r] = sum_j W_l[k][j] * Wih[r][j]   (gi = S @ WC; r = gate*64+c)
//  WTh[k*192 + r]    = Whh[r][k]
//  B[0..191]=bih, B[192..383]=bhh
#define N_WCT 36864
#define N_WTH 12288
#define N_B   384
template <bool F32>
__device__ __forceinline__ void wc_body(const void* W, const void* Wih, const void* Whh,
                                        const void* bih, const void* bhh,
                                        float* WCT, float* WTh, float* B) {
    int i = blockIdx.x * 256 + threadIdx.x;
    if (i < N_WCT) {
        int l = i / 12288, rem = i % 12288, k = rem / 192, r = rem % 192;
        float acc = 0.f;
#pragma unroll 8
        for (int j = 0; j < 64; ++j)
            acc = fmaf(ld<F32>(W, l * 4096 + k * 64 + j), ld<F32>(Wih, r * 64 + j), acc);
        WCT[i] = acc;
    } else if (i < N_WCT + N_WTH) {
        int rem = i - N_WCT;
        int k = rem / 192, r = rem % 192;
        WTh[rem] = ld<F32>(Whh, r * 64 + k);
    } else if (i < N_WCT + N_WTH + N_B) {
        int rem = i - N_WCT - N_WTH;
        B[rem] = (rem < 192) ? ld<F32>(bih, rem) : ld<F32>(bhh, rem - 192);
    }
}
__global__ __launch_bounds__(256) void wc_prep(const int* flags, const void* W, const void* Wih,
                                               const void* Whh, const void* bih, const void* bhh,
                                               float* WCT, float* WTh, float* B) {
    if (flags[0]) wc_body<true>(W, Wih, Whh, bih, bhh, WCT, WTh, B);
    else          wc_body<false>(W, Wih, Whh, bih, bhh, WCT, WTh, B);
}

// ================= CSR build (dst-major), once per call =================
__global__ __launch_bounds__(256) void hist_kernel(const int* __restrict__ flags,
                                                   const int* __restrict__ ei,
                                                   int* __restrict__ cnt, int E, int N) {
    int i = blockIdx.x * 256 + threadIdx.x;
    if (i >= E) return;
    int dst = flags[1] ? ei[E + i] : ei[2 * (E + i)];
    if ((unsigned)dst < (unsigned)N) atomicAdd(&cnt[dst], 1);
}
__global__ __launch_bounds__(256) void scan1_kernel(const int* __restrict__ cnt,
                                                    int* __restrict__ bsum, int N) {
    __shared__ int sm[256];
    int t = threadIdx.x, i = blockIdx.x * 256 + t;
    sm[t] = (i < N) ? cnt[i] : 0;
    __syncthreads();
    for (int s = 128; s > 0; s >>= 1) {
        if (t < s) sm[t] += sm[t + s];
        __syncthreads();
    }
    if (t == 0) bsum[blockIdx.x] = sm[0];
}
__global__ __launch_bounds__(256) void scan2_kernel(const int* __restrict__ bsum,
                                                    int* __restrict__ boff,
                                                    int* __restrict__ rs, int NB, int N) {
    __shared__ int sm[256];
    int t = threadIdx.x;
    int v = (t < NB) ? bsum[t] : 0;
    sm[t] = v;
    __syncthreads();
    for (int off = 1; off < 256; off <<= 1) {
        int u = (t >= off) ? sm[t - off] : 0;
        __syncthreads();
        sm[t] += u;
        __syncthreads();
    }
    boff[t] = sm[t] - v;
    if (t == 255) rs[N] = sm[255];
}
// writes rs[i] AND seeds cur[i]=rs[i] so fill needs no second memset
__global__ __launch_bounds__(256) void scan3_kernel(const int* __restrict__ cnt,
                                                    const int* __restrict__ boff,
                                                    int* __restrict__ rs,
                                                    int* __restrict__ cur, int N) {
    __shared__ int sm[256];
    int t = threadIdx.x, i = blockIdx.x * 256 + t;
    int v = (i < N) ? cnt[i] : 0;
    sm[t] = v;
    __syncthreads();
    for (int off = 1; off < 256; off <<= 1) {
        int u = (t >= off) ? sm[t - off] : 0;
        __syncthreads();
        sm[t] += u;
        __syncthreads();
    }
    if (i < N) { int r = boff[blockIdx.x] + sm[t] - v; rs[i] = r; cur[i] = r; }
}
__global__ __launch_bounds__(256) void fill_kernel(const int* __restrict__ flags,
                                                   const int* __restrict__ ei,
                                                   int* __restrict__ cur,
                                                   int* __restrict__ ss, int E, int N) {
    int i = blockIdx.x * 256 + threadIdx.x;
    if (i >= E) return;
    int src, dst;
    if (flags[1]) { src = ei[i];     dst = ei[E + i]; }
    else          { src = ei[2 * i]; dst = ei[2 * (E + i)]; }
    if ((unsigned)src >= (unsigned)N || (unsigned)dst >= (unsigned)N) return;
    int pos = atomicAdd(&cur[dst], 1);
    ss[pos] = src;
}

// ======= fused layer: gather-sum(h[src]) -> GRU gates via combined WC =======
// Block = 256 threads = 16 nodes; lane = channel; each wave owns 4 nodes.
__global__ __launch_bounds__(256) void layer_fused(const int* __restrict__ flags,
                                                   const float* __restrict__ hcur,
                                                   const int* __restrict__ rs,
                                                   const int* __restrict__ ss,
                                                   const float* __restrict__ WC,   // layer slice [64][192] k-major
                                                   const float* __restrict__ WTh,  // [64][192] k-major
                                                   const float* __restrict__ B,    // 384 fp32
                                                   float* __restrict__ outp,       // mid layers
                                                   void* __restrict__ dout,        // last layer
                                                   int N) {
    __shared__ float LA[16 * 66];
    __shared__ float LH[16 * 66];
    int t = threadIdx.x;
    int n0 = blockIdx.x * 16;
    int lane = t & 63;
    int w4 = (t >> 6) * 4;

    {   // stage own h rows (coalesced float4)
        int row = t >> 4, col = (t & 15) * 4;
        bool v = (n0 + row) < N;
        float4 vh = v ? *(const float4*)(hcur + (size_t)(n0 + row) * D + col)
                      : make_float4(0.f, 0.f, 0.f, 0.f);
        LH[row * 66 + col + 0] = vh.x; LH[row * 66 + col + 1] = vh.y;
        LH[row * 66 + col + 2] = vh.z; LH[row * 66 + col + 3] = vh.w;
    }
    // gather: sum of incoming h rows per node (coalesced 256B row reads, 8-way MLP)
#pragma unroll 1
    for (int nn = 0; nn < 4; ++nn) {
        int n = n0 + w4 + nn;  // wave-uniform
        float acc = 0.f;
        if (n < N) {
            int s = rs[n], e2 = rs[n + 1];
            int j = s;
            for (; j + 7 < e2; j += 8) {
                int i0 = ss[j], i1 = ss[j + 1], i2 = ss[j + 2], i3 = ss[j + 3];
                int i4 = ss[j + 4], i5 = ss[j + 5], i6 = ss[j + 6], i7 = ss[j + 7];
                float a0 = hcur[(size_t)i0 * D + lane];
                float a1 = hcur[(size_t)i1 * D + lane];
                float a2 = hcur[(size_t)i2 * D + lane];
                float a3 = hcur[(size_t)i3 * D + lane];
                float a4 = hcur[(size_t)i4 * D + lane];
                float a5 = hcur[(size_t)i5 * D + lane];
                float a6 = hcur[(size_t)i6 * D + lane];
                float a7 = hcur[(size_t)i7 * D + lane];
                acc += ((a0 + a1) + (a2 + a3)) + ((a4 + a5) + (a6 + a7));
            }
            for (; j < e2; ++j) acc += hcur[(size_t)ss[j] * D + lane];
        }
        LA[(w4 + nn) * 66 + lane] = acc;
    }
    __syncthreads();

    // gates: lane = channel c; k-major weight rows; LDS reads as float2 (b64)
    float ra[4], za[4], ia[4], ha[4];
    {
        float br = B[lane] + B[192 + lane];
        float bz = B[64 + lane] + B[256 + lane];
        float bi = B[128 + lane];
        float bh = B[320 + lane];
#pragma unroll
        for (int nn = 0; nn < 4; ++nn) { ra[nn] = br; za[nn] = bz; ia[nn] = bi; ha[nn] = bh; }
    }
#pragma unroll 2
    for (int kk = 0; kk < 32; ++kk) {
        int k0 = 2 * kk;
        float w0a = WC[k0 * 192 + lane];
        float w1a = WC[k0 * 192 + 64 + lane];
        float w2a = WC[k0 * 192 + 128 + lane];
        float w0b = WC[(k0 + 1) * 192 + lane];
        float w1b = WC[(k0 + 1) * 192 + 64 + lane];
        float w2b = WC[(k0 + 1) * 192 + 128 + lane];
        float v0a = WTh[k0 * 192 + lane];
        float v1a = WTh[k0 * 192 + 64 + lane];
        float v2a = WTh[k0 * 192 + 128 + lane];
        float v0b = WTh[(k0 + 1) * 192 + lane];
        float v1b = WTh[(k0 + 1) * 192 + 64 + lane];
        float v2b = WTh[(k0 + 1) * 192 + 128 + lane];
#pragma unroll
        for (int nn = 0; nn < 4; ++nn) {
            int rr = w4 + nn;
            float2 a = *(const float2*)&LA[rr * 66 + k0];
            float2 hh = *(const float2*)&LH[rr * 66 + k0];
            ra[nn] = fmaf(a.x, w0a, fmaf(hh.x, v0a, ra[nn]));
            ra[nn] = fmaf(a.y, w0b, fmaf(hh.y, v0b, ra[nn]));
            za[nn] = fmaf(a.x, w1a, fmaf(hh.x, v1a, za[nn]));
            za[nn] = fmaf(a.y, w1b, fmaf(hh.y, v1b, za[nn]));
            ia[nn] = fmaf(a.x, w2a, ia[nn]);
            ia[nn] = fmaf(a.y, w2b, ia[nn]);
            ha[nn] = fmaf(hh.x, v2a, ha[nn]);
            ha[nn] = fmaf(hh.y, v2b, ha[nn]);
        }
    }
#pragma unroll
    for (int nn = 0; nn < 4; ++nn) {
        int n = n0 + w4 + nn;
        float r = 1.f / (1.f + __expf(-ra[nn]));
        float z = 1.f / (1.f + __expf(-za[nn]));
        float nx = ia[nn] + r * ha[nn];
        float tnh = 1.f - 2.f / (1.f + __expf(2.f * nx));  // tanh, overflow-safe
        float hn = (1.f - z) * tnh + z * LH[(w4 + nn) * 66 + lane];
        if (n < N) {
            if (outp) outp[(size_t)n * D + lane] = hn;
            else if (flags[0]) ((float*)dout)[(size_t)n * D + lane] = hn;
            else ((bf16*)dout)[(size_t)n * D + lane] = __float2bfloat16(hn);
        }
    }
}

extern "C" void kernel_launch(void* const* d_in, const int* in_sizes, int n_in,
                              void* d_out, int out_size, void* d_ws, size_t ws_size,
                              hipStream_t stream) {
    const void* x   = d_in[0];
    const int*  ei  = (const int*)d_in[1];
    const void* Wnt = d_in[4];
    const void* bnt = d_in[5];
    const void* Wt  = d_in[6];   // [3,64,64]
    const void* Wih = d_in[7];   // [192,64]
    const void* Whh = d_in[8];
    const void* bih = d_in[9];
    const void* bhh = d_in[10];

    int N = in_sizes[0] / 6;
    int E = in_sizes[1] / 2;
    int ND = N * D;
    int NB = (N + 255) / 256;

    // Workspace (within proven 38.4 MB): flags | hA | hB | CSR+weights
    int* flags = (int*)d_ws;
    float* hA = (float*)((char*)d_ws + 256);
    float* hB = hA + ND;
    char* C = (char*)(hB + ND);
    int* rs   = (int*)C;                 // N+1
    int* cnt  = rs + (N + 1);            // N
    int* cur  = cnt + N;                 // N
    int* bsum = cur + N;                 // 256
    int* boff = bsum + 256;              // 256
    int* ss   = boff + 256;              // E
    float* WCT = (float*)(ss + E);       // 36864
    float* WTh = WCT + N_WCT;            // 12288
    float* B   = WTh + N_WTH;            // 384

    detect_kernel<<<1, 256, 0, stream>>>(x, ei, flags);
    nt_kernel<<<(ND + 255) / 256, 256, 0, stream>>>(flags, x, Wnt, bnt, hA, N);
    wc_prep<<<(N_WCT + N_WTH + N_B + 255) / 256, 256, 0, stream>>>(flags, Wt, Wih, Whh,
                                                                   bih, bhh, WCT, WTh, B);
    hipMemsetAsync(cnt, 0, (size_t)N * sizeof(int), stream);
    hist_kernel<<<(E + 255) / 256, 256, 0, stream>>>(flags, ei, cnt, E, N);
    scan1_kernel<<<NB, 256, 0, stream>>>(cnt, bsum, N);
    scan2_kernel<<<1, 256, 0, stream>>>(bsum, boff, rs, NB, N);
    scan3_kernel<<<NB, 256, 0, stream>>>(cnt, boff, rs, cur, N);
    fill_kernel<<<(E + 255) / 256, 256, 0, stream>>>(flags, ei, cur, ss, E, N);

    float* hcur = hA;
    float* hnxt = hB;
    for (int layer = 0; layer < 3; ++layer) {
        bool last = (layer == 2);
        layer_fused<<<(N + 15) / 16, 256, 0, stream>>>(flags, hcur, rs, ss,
                                                       WCT + layer * 12288, WTh, B,
                                                       last ? nullptr : hnxt,
                                                       last ? d_out : nullptr, N);
        float* t = hcur; hcur = hnxt; hnxt = t;
    }
}

// Round 12
// 461.756 us; speedup vs baseline: 4.6979x; 1.1131x over previous
//
#include <hip/hip_runtime.h>
#include <hip/hip_bf16.h>
#include <stdint.h>

#define D 64
typedef __hip_bfloat16 bf16;
typedef unsigned short u16;

__device__ __forceinline__ float bf2f(u16 u) { return __uint_as_float(((uint32_t)u) << 16); }

template <bool F32>
__device__ __forceinline__ float ld(const void* p, int i) {
    if constexpr (F32) return ((const float*)p)[i];
    else return bf2f(((const u16*)p)[i]);
}

// ---- dtype oracle (proven): flags[0]=1 -> fp32 floats; flags[1]=1 -> int32 idx ----
__global__ __launch_bounds__(256) void detect_kernel(const void* x, const int* ei, int* flags) {
    __shared__ float smax[256];
    __shared__ int sor[256];
    int t = threadIdx.x;
    const u16* xs = (const u16*)x;
    float mx = 0.f;
#pragma unroll
    for (int i = 0; i < 16; ++i) {
        float a = fabsf(bf2f(xs[t * 16 + i]));
        if (!(a == a)) a = 1e30f;
        mx = fmaxf(mx, a);
    }
    int any = 0;
#pragma unroll
    for (int i = 0; i < 8; ++i) any |= ei[2 * (t * 8 + i) + 1];
    smax[t] = mx; sor[t] = any;
    __syncthreads();
    for (int s = 128; s > 0; s >>= 1) {
        if (t < s) { smax[t] = fmaxf(smax[t], smax[t + s]); sor[t] |= sor[t + s]; }
        __syncthreads();
    }
    if (t == 0) { flags[0] = (smax[0] > 1000.f) ? 1 : 0; flags[1] = (sor[0] != 0) ? 1 : 0; }
}

// ---- prep_all: one dispatch = nt (h0 -> bf16 table) + combined weights + hist ----
//  WCT[l][k*192 + r] = sum_j W_l[k][j] * Wih[r][j]   (gi = S @ WC; r = gate*64+c)
//  WTh[k*192 + r]    = Whh[r][k];  B[0..191]=bih, B[192..383]=bhh
#define N_WCT 36864
#define N_WTH 12288
#define N_B   384
template <bool F32>
__device__ __forceinline__ void nt_body(const void* x, const void* Wnt, const void* bnt,
                                        u16* ht, int N, int blk) {
    int gid = blk * 256 + threadIdx.x;
    if (gid >= N * D) return;
    int n = gid >> 6, c = gid & 63;
    float acc = ld<F32>(bnt, c);
#pragma unroll
    for (int k = 0; k < 6; ++k)
        acc = fmaf(ld<F32>(x, n * 6 + k), ld<F32>(Wnt, c * 6 + k), acc);
    ht[gid] = (u16)(__bfloat16_as_ushort(__float2bfloat16(fmaxf(acc, 0.f))));
}
template <bool F32>
__device__ __forceinline__ void wc_body(const void* W, const void* Wih, const void* Whh,
                                        const void* bih, const void* bhh,
                                        float* WCT, float* WTh, float* B, int blk) {
    int i = blk * 256 + threadIdx.x;
    if (i < N_WCT) {
        int l = i / 12288, rem = i % 12288, k = rem / 192, r = rem % 192;
        float acc = 0.f;
#pragma unroll 8
        for (int j = 0; j < 64; ++j)
            acc = fmaf(ld<F32>(W, l * 4096 + k * 64 + j), ld<F32>(Wih, r * 64 + j), acc);
        WCT[i] = acc;
    } else if (i < N_WCT + N_WTH) {
        int rem = i - N_WCT;
        int k = rem / 192, r = rem % 192;
        WTh[rem] = ld<F32>(Whh, r * 64 + k);
    } else if (i < N_WCT + N_WTH + N_B) {
        int rem = i - N_WCT - N_WTH;
        B[rem] = (rem < 192) ? ld<F32>(bih, rem) : ld<F32>(bhh, rem - 192);
    }
}
__global__ __launch_bounds__(256) void prep_all(const int* __restrict__ flags,
                                                const void* x, const void* Wnt, const void* bnt,
                                                const void* W, const void* Wih, const void* Whh,
                                                const void* bih, const void* bhh,
                                                u16* ht, float* WCT, float* WTh, float* B,
                                                const int* __restrict__ ei, int* __restrict__ cnt,
                                                int E, int N, int NT_BLK, int WC_BLK) {
    int b = blockIdx.x;
    if (b < NT_BLK) {
        if (flags[0]) nt_body<true>(x, Wnt, bnt, ht, N, b);
        else          nt_body<false>(x, Wnt, bnt, ht, N, b);
    } else if (b < NT_BLK + WC_BLK) {
        if (flags[0]) wc_body<true>(W, Wih, Whh, bih, bhh, WCT, WTh, B, b - NT_BLK);
        else          wc_body<false>(W, Wih, Whh, bih, bhh, WCT, WTh, B, b - NT_BLK);
    } else {
        int i = (b - NT_BLK - WC_BLK) * 256 + threadIdx.x;
        if (i >= E) return;
        int dst = flags[1] ? ei[E + i] : ei[2 * (E + i)];
        if ((unsigned)dst < (unsigned)N) atomicAdd(&cnt[dst], 1);
    }
}

// ================= CSR scan chain (proven) =================
__global__ __launch_bounds__(256) void scan1_kernel(const int* __restrict__ cnt,
                                                    int* __restrict__ bsum, int N) {
    __shared__ int sm[256];
    int t = threadIdx.x, i = blockIdx.x * 256 + t;
    sm[t] = (i < N) ? cnt[i] : 0;
    __syncthreads();
    for (int s = 128; s > 0; s >>= 1) {
        if (t < s) sm[t] += sm[t + s];
        __syncthreads();
    }
    if (t == 0) bsum[blockIdx.x] = sm[0];
}
__global__ __launch_bounds__(256) void scan2_kernel(const int* __restrict__ bsum,
                                                    int* __restrict__ boff,
                                                    int* __restrict__ rs, int NB, int N) {
    __shared__ int sm[256];
    int t = threadIdx.x;
    int v = (t < NB) ? bsum[t] : 0;
    sm[t] = v;
    __syncthreads();
    for (int off = 1; off < 256; off <<= 1) {
        int u = (t >= off) ? sm[t - off] : 0;
        __syncthreads();
        sm[t] += u;
        __syncthreads();
    }
    boff[t] = sm[t] - v;
    if (t == 255) rs[N] = sm[255];
}
__global__ __launch_bounds__(256) void scan3_kernel(const int* __restrict__ cnt,
                                                    const int* __restrict__ boff,
                                                    int* __restrict__ rs,
                                                    int* __restrict__ cur, int N) {
    __shared__ int sm[256];
    int t = threadIdx.x, i = blockIdx.x * 256 + t;
    int v = (i < N) ? cnt[i] : 0;
    sm[t] = v;
    __syncthreads();
    for (int off = 1; off < 256; off <<= 1) {
        int u = (t >= off) ? sm[t - off] : 0;
        __syncthreads();
        sm[t] += u;
        __syncthreads();
    }
    if (i < N) { int r = boff[blockIdx.x] + sm[t] - v; rs[i] = r; cur[i] = r; }
}
__global__ __launch_bounds__(256) void fill_kernel(const int* __restrict__ flags,
                                                   const int* __restrict__ ei,
                                                   int* __restrict__ cur,
                                                   int* __restrict__ ss, int E, int N) {
    int i = blockIdx.x * 256 + threadIdx.x;
    if (i >= E) return;
    int src, dst;
    if (flags[1]) { src = ei[i];     dst = ei[E + i]; }
    else          { src = ei[2 * i]; dst = ei[2 * (E + i)]; }
    if ((unsigned)src >= (unsigned)N || (unsigned)dst >= (unsigned)N) return;
    int pos = atomicAdd(&cur[dst], 1);
    ss[pos] = src;
}

// ======= fused layer: bf16-gather-sum(h[src]) -> GRU gates via combined WC =======
// Block = 256 threads = 16 nodes; lane = channel; each wave owns 4 nodes.
__global__ __launch_bounds__(256) void layer_fused(const int* __restrict__ flags,
                                                   const u16* __restrict__ ht,   // bf16 h table
                                                   const int* __restrict__ rs,
                                                   const int* __restrict__ ss,
                                                   const float* __restrict__ WC,   // [64][192] k-major
                                                   const float* __restrict__ WTh,  // [64][192] k-major
                                                   const float* __restrict__ B,    // 384 fp32
                                                   u16* __restrict__ houtb,        // mid layers (bf16)
                                                   void* __restrict__ dout,        // last layer
                                                   int N) {
    __shared__ float LA[16 * 66];
    __shared__ float LH[16 * 66];
    int t = threadIdx.x;
    int n0 = blockIdx.x * 16;
    int lane = t & 63;
    int w4 = (t >> 6) * 4;

    {   // stage own h rows (coalesced 8B bf16x4 loads, unpack to fp32 LDS)
        int row = t >> 4, col = (t & 15) * 4;
        bool v = (n0 + row) < N;
        ushort4 vh = {0, 0, 0, 0};
        if (v) vh = *(const ushort4*)(ht + (size_t)(n0 + row) * D + col);
        LH[row * 66 + col + 0] = bf2f(vh.x); LH[row * 66 + col + 1] = bf2f(vh.y);
        LH[row * 66 + col + 2] = bf2f(vh.z); LH[row * 66 + col + 3] = bf2f(vh.w);
    }
    // gather: sum of incoming bf16 h rows per node (128B row reads, 8-way MLP)
#pragma unroll 1
    for (int nn = 0; nn < 4; ++nn) {
        int n = n0 + w4 + nn;  // wave-uniform
        float acc = 0.f;
        if (n < N) {
            int s = rs[n], e2 = rs[n + 1];
            int j = s;
            for (; j + 7 < e2; j += 8) {
                int i0 = ss[j], i1 = ss[j + 1], i2 = ss[j + 2], i3 = ss[j + 3];
                int i4 = ss[j + 4], i5 = ss[j + 5], i6 = ss[j + 6], i7 = ss[j + 7];
                float a0 = bf2f(ht[(size_t)i0 * D + lane]);
                float a1 = bf2f(ht[(size_t)i1 * D + lane]);
                float a2 = bf2f(ht[(size_t)i2 * D + lane]);
                float a3 = bf2f(ht[(size_t)i3 * D + lane]);
                float a4 = bf2f(ht[(size_t)i4 * D + lane]);
                float a5 = bf2f(ht[(size_t)i5 * D + lane]);
                float a6 = bf2f(ht[(size_t)i6 * D + lane]);
                float a7 = bf2f(ht[(size_t)i7 * D + lane]);
                acc += ((a0 + a1) + (a2 + a3)) + ((a4 + a5) + (a6 + a7));
            }
            for (; j < e2; ++j) acc += bf2f(ht[(size_t)ss[j] * D + lane]);
        }
        LA[(w4 + nn) * 66 + lane] = acc;
    }
    __syncthreads();

    // gates: lane = channel c; k-major weight rows; LDS reads as float2 (proven round-11)
    float ra[4], za[4], ia[4], ha[4];
    {
        float br = B[lane] + B[192 + lane];
        float bz = B[64 + lane] + B[256 + lane];
        float bi = B[128 + lane];
        float bh = B[320 + lane];
#pragma unroll
        for (int nn = 0; nn < 4; ++nn) { ra[nn] = br; za[nn] = bz; ia[nn] = bi; ha[nn] = bh; }
    }
#pragma unroll 2
    for (int kk = 0; kk < 32; ++kk) {
        int k0 = 2 * kk;
        float w0a = WC[k0 * 192 + lane];
        float w1a = WC[k0 * 192 + 64 + lane];
        float w2a = WC[k0 * 192 + 128 + lane];
        float w0b = WC[(k0 + 1) * 192 + lane];
        float w1b = WC[(k0 + 1) * 192 + 64 + lane];
        float w2b = WC[(k0 + 1) * 192 + 128 + lane];
        float v0a = WTh[k0 * 192 + lane];
        float v1a = WTh[k0 * 192 + 64 + lane];
        float v2a = WTh[k0 * 192 + 128 + lane];
        float v0b = WTh[(k0 + 1) * 192 + lane];
        float v1b = WTh[(k0 + 1) * 192 + 64 + lane];
        float v2b = WTh[(k0 + 1) * 192 + 128 + lane];
#pragma unroll
        for (int nn = 0; nn < 4; ++nn) {
            int rr = w4 + nn;
            float2 a = *(const float2*)&LA[rr * 66 + k0];
            float2 hh = *(const float2*)&LH[rr * 66 + k0];
            ra[nn] = fmaf(a.x, w0a, fmaf(hh.x, v0a, ra[nn]));
            ra[nn] = fmaf(a.y, w0b, fmaf(hh.y, v0b, ra[nn]));
            za[nn] = fmaf(a.x, w1a, fmaf(hh.x, v1a, za[nn]));
            za[nn] = fmaf(a.y, w1b, fmaf(hh.y, v1b, za[nn]));
            ia[nn] = fmaf(a.x, w2a, ia[nn]);
            ia[nn] = fmaf(a.y, w2b, ia[nn]);
            ha[nn] = fmaf(hh.x, v2a, ha[nn]);
            ha[nn] = fmaf(hh.y, v2b, ha[nn]);
        }
    }
#pragma unroll
    for (int nn = 0; nn < 4; ++nn) {
        int n = n0 + w4 + nn;
        float r = 1.f / (1.f + __expf(-ra[nn]));
        float z = 1.f / (1.f + __expf(-za[nn]));
        float nx = ia[nn] + r * ha[nn];
        float tnh = 1.f - 2.f / (1.f + __expf(2.f * nx));  // tanh, overflow-safe
        float hn = (1.f - z) * tnh + z * LH[(w4 + nn) * 66 + lane];
        if (n < N) {
            size_t idx = (size_t)n * D + lane;
            if (houtb) houtb[idx] = __bfloat16_as_ushort(__float2bfloat16(hn));
            else if (flags[0]) ((float*)dout)[idx] = hn;
            else ((bf16*)dout)[idx] = __float2bfloat16(hn);
        }
    }
}

extern "C" void kernel_launch(void* const* d_in, const int* in_sizes, int n_in,
                              void* d_out, int out_size, void* d_ws, size_t ws_size,
                              hipStream_t stream) {
    const void* x   = d_in[0];
    const int*  ei  = (const int*)d_in[1];
    const void* Wnt = d_in[4];
    const void* bnt = d_in[5];
    const void* Wt  = d_in[6];   // [3,64,64]
    const void* Wih = d_in[7];   // [192,64]
    const void* Whh = d_in[8];
    const void* bih = d_in[9];
    const void* bhh = d_in[10];

    int N = in_sizes[0] / 6;
    int E = in_sizes[1] / 2;
    int ND = N * D;
    int NB = (N + 255) / 256;

    // Workspace (~17 MB, well within proven 38.4 MB):
    // flags | htA (bf16) | htB (bf16) | rs | cnt | cur | bsum | boff | ss | WCT | WTh | B
    int* flags = (int*)d_ws;
    u16* htA = (u16*)((char*)d_ws + 256);
    u16* htB = htA + ND;
    int* rs   = (int*)(htB + ND);
    int* cnt  = rs + (N + 1);
    int* cur  = cnt + N;
    int* bsum = cur + N;
    int* boff = bsum + 256;
    int* ss   = boff + 256;
    float* WCT = (float*)(ss + E);       // 36864
    float* WTh = WCT + N_WCT;            // 12288
    float* B   = WTh + N_WTH;            // 384

    int NT_BLK = (ND + 255) / 256;
    int WC_BLK = (N_WCT + N_WTH + N_B + 255) / 256;
    int HI_BLK = (E + 255) / 256;

    hipMemsetAsync(cnt, 0, (size_t)N * sizeof(int), stream);
    detect_kernel<<<1, 256, 0, stream>>>(x, ei, flags);
    prep_all<<<NT_BLK + WC_BLK + HI_BLK, 256, 0, stream>>>(flags, x, Wnt, bnt, Wt, Wih, Whh,
                                                           bih, bhh, htA, WCT, WTh, B,
                                                           ei, cnt, E, N, NT_BLK, WC_BLK);
    scan1_kernel<<<NB, 256, 0, stream>>>(cnt, bsum, N);
    scan2_kernel<<<1, 256, 0, stream>>>(bsum, boff, rs, NB, N);
    scan3_kernel<<<NB, 256, 0, stream>>>(cnt, boff, rs, cur, N);
    fill_kernel<<<(E + 255) / 256, 256, 0, stream>>>(flags, ei, cur, ss, E, N);

    u16* hcur = htA;
    u16* hnxt = htB;
    for (int layer = 0; layer < 3; ++layer) {
        bool last = (layer == 2);
        layer_fused<<<(N + 15) / 16, 256, 0, stream>>>(flags, hcur, rs, ss,
                                                       WCT + layer * 12288, WTh, B,
                                                       last ? nullptr : hnxt,
                                                       last ? d_out : nullptr, N);
        u16* t = hcur; hcur = hnxt; hnxt = t;
    }
}

// Round 13
// 404.228 us; speedup vs baseline: 5.3665x; 1.1423x over previous
//
#include <hip/hip_runtime.h>
#include <hip/hip_bf16.h>
#include <stdint.h>

#define D 64
typedef __hip_bfloat16 bf16;
typedef unsigned short u16;

__device__ __forceinline__ float bf2f(u16 u) { return __uint_as_float(((uint32_t)u) << 16); }

template <bool F32>
__device__ __forceinline__ float ld(const void* p, int i) {
    if constexpr (F32) return ((const float*)p)[i];
    else return bf2f(((const u16*)p)[i]);
}

// ---- dtype oracle (proven): flags[0]=1 -> fp32 floats; flags[1]=1 -> int32 idx ----
__global__ __launch_bounds__(256) void detect_kernel(const void* x, const int* ei, int* flags) {
    __shared__ float smax[256];
    __shared__ int sor[256];
    int t = threadIdx.x;
    const u16* xs = (const u16*)x;
    float mx = 0.f;
#pragma unroll
    for (int i = 0; i < 16; ++i) {
        float a = fabsf(bf2f(xs[t * 16 + i]));
        if (!(a == a)) a = 1e30f;
        mx = fmaxf(mx, a);
    }
    int any = 0;
#pragma unroll
    for (int i = 0; i < 8; ++i) any |= ei[2 * (t * 8 + i) + 1];
    smax[t] = mx; sor[t] = any;
    __syncthreads();
    for (int s = 128; s > 0; s >>= 1) {
        if (t < s) { smax[t] = fmaxf(smax[t], smax[t + s]); sor[t] |= sor[t + s]; }
        __syncthreads();
    }
    if (t == 0) { flags[0] = (smax[0] > 1000.f) ? 1 : 0; flags[1] = (sor[0] != 0) ? 1 : 0; }
}

// ---- prep_all: nt (h0 -> bf16 table) + combined weights + direct bucket fill ----
//  WCT[l][k*192 + r] = sum_j W_l[k][j] * Wih[r][j]   (gi = S @ WC; r = gate*64+c)
//  WTh[k*192 + r]    = Whh[r][k];  B[0..191]=bih, B[192..383]=bhh
#define N_WCT 36864
#define N_WTH 12288
#define N_B   384
template <bool F32>
__device__ __forceinline__ void nt_body(const void* x, const void* Wnt, const void* bnt,
                                        u16* ht, int N, int blk) {
    int gid = blk * 256 + threadIdx.x;
    if (gid >= N * D) return;
    int n = gid >> 6, c = gid & 63;
    float acc = ld<F32>(bnt, c);
#pragma unroll
    for (int k = 0; k < 6; ++k)
        acc = fmaf(ld<F32>(x, n * 6 + k), ld<F32>(Wnt, c * 6 + k), acc);
    ht[gid] = __bfloat16_as_ushort(__float2bfloat16(fmaxf(acc, 0.f)));
}
template <bool F32>
__device__ __forceinline__ void wc_body(const void* W, const void* Wih, const void* Whh,
                                        const void* bih, const void* bhh,
                                        float* WCT, float* WTh, float* B, int blk) {
    int i = blk * 256 + threadIdx.x;
    if (i < N_WCT) {
        int l = i / 12288, rem = i % 12288, k = rem / 192, r = rem % 192;
        float acc = 0.f;
#pragma unroll 8
        for (int j = 0; j < 64; ++j)
            acc = fmaf(ld<F32>(W, l * 4096 + k * 64 + j), ld<F32>(Wih, r * 64 + j), acc);
        WCT[i] = acc;
    } else if (i < N_WCT + N_WTH) {
        int rem = i - N_WCT;
        int k = rem / 192, r = rem % 192;
        WTh[rem] = ld<F32>(Whh, r * 64 + k);
    } else if (i < N_WCT + N_WTH + N_B) {
        int rem = i - N_WCT - N_WTH;
        B[rem] = (rem < 192) ? ld<F32>(bih, rem) : ld<F32>(bhh, rem - 192);
    }
}
__global__ __launch_bounds__(256) void prep_all(const int* __restrict__ flags,
                                                const void* x, const void* Wnt, const void* bnt,
                                                const void* W, const void* Wih, const void* Whh,
                                                const void* bih, const void* bhh,
                                                u16* ht, float* WCT, float* WTh, float* B,
                                                const int* __restrict__ ei, int* __restrict__ cnt,
                                                u16* __restrict__ ss16, int* __restrict__ novf,
                                                int* __restrict__ ovf,
                                                int E, int N, int NT_BLK, int WC_BLK) {
    int b = blockIdx.x;
    if (b < NT_BLK) {
        if (flags[0]) nt_body<true>(x, Wnt, bnt, ht, N, b);
        else          nt_body<false>(x, Wnt, bnt, ht, N, b);
    } else if (b < NT_BLK + WC_BLK) {
        if (flags[0]) wc_body<true>(W, Wih, Whh, bih, bhh, WCT, WTh, B, b - NT_BLK);
        else          wc_body<false>(W, Wih, Whh, bih, bhh, WCT, WTh, B, b - NT_BLK);
    } else {
        // fill_direct: one atomic counts AND allocates the bucket slot
        int i = (b - NT_BLK - WC_BLK) * 256 + threadIdx.x;
        if (i >= E) return;
        int src, dst;
        if (flags[1]) { src = ei[i];     dst = ei[E + i]; }
        else          { src = ei[2 * i]; dst = ei[2 * (E + i)]; }
        if ((unsigned)src >= (unsigned)N || (unsigned)dst >= (unsigned)N) return;
        int pos = atomicAdd(&cnt[dst], 1);
        if (pos < 64) ss16[(size_t)dst * 64 + pos] = (u16)src;
        else { int o = atomicAdd(novf, 1); ovf[2 * o] = dst; ovf[2 * o + 1] = src; }
    }
}

// ======= fused layer: bucket-gather-sum(h[src]) -> GRU gates via combined WC =======
// Block = 256 threads = 16 nodes; lane = channel; each wave owns 4 nodes.
__global__ __launch_bounds__(256) void layer_fused(const int* __restrict__ flags,
                                                   const u16* __restrict__ ht,
                                                   const int* __restrict__ cnt,
                                                   const u16* __restrict__ ss16,
                                                   const int* __restrict__ novf,
                                                   const int* __restrict__ ovf,
                                                   const float* __restrict__ WC,   // [64][192] k-major
                                                   const float* __restrict__ WTh,  // [64][192] k-major
                                                   const float* __restrict__ B,    // 384 fp32
                                                   u16* __restrict__ houtb,        // mid layers (bf16)
                                                   void* __restrict__ dout,        // last layer
                                                   int N) {
    __shared__ float LA[16 * 66];
    __shared__ float LH[16 * 66];
    int t = threadIdx.x;
    int n0 = blockIdx.x * 16;
    int lane = t & 63;
    int w4 = (t >> 6) * 4;

    {   // stage own h rows (coalesced 8B bf16x4 loads, unpack to fp32 LDS)
        int row = t >> 4, col = (t & 15) * 4;
        bool v = (n0 + row) < N;
        ushort4 vh = {0, 0, 0, 0};
        if (v) vh = *(const ushort4*)(ht + (size_t)(n0 + row) * D + col);
        LH[row * 66 + col + 0] = bf2f(vh.x); LH[row * 66 + col + 1] = bf2f(vh.y);
        LH[row * 66 + col + 2] = bf2f(vh.z); LH[row * 66 + col + 3] = bf2f(vh.w);
    }
    // gather: sum incoming bf16 h rows per node; 16/8/4-wide batches for MLP
#pragma unroll 1
    for (int nn = 0; nn < 4; ++nn) {
        int n = n0 + w4 + nn;  // wave-uniform
        float acc = 0.f;
        if (n < N) {
            int dg = cnt[n]; if (dg > 64) dg = 64;
            const u16* bp = ss16 + (size_t)n * 64;
            int j = 0;
            for (; j + 15 < dg; j += 16) {
                int ix[16];
#pragma unroll
                for (int q = 0; q < 16; ++q) ix[q] = bp[j + q];
                float a[16];
#pragma unroll
                for (int q = 0; q < 16; ++q) a[q] = bf2f(ht[(size_t)ix[q] * D + lane]);
                acc += (((a[0] + a[1]) + (a[2] + a[3])) + ((a[4] + a[5]) + (a[6] + a[7])))
                     + (((a[8] + a[9]) + (a[10] + a[11])) + ((a[12] + a[13]) + (a[14] + a[15])));
            }
            for (; j + 7 < dg; j += 8) {
                int ix[8];
#pragma unroll
                for (int q = 0; q < 8; ++q) ix[q] = bp[j + q];
                float a[8];
#pragma unroll
                for (int q = 0; q < 8; ++q) a[q] = bf2f(ht[(size_t)ix[q] * D + lane]);
                acc += ((a[0] + a[1]) + (a[2] + a[3])) + ((a[4] + a[5]) + (a[6] + a[7]));
            }
            for (; j + 3 < dg; j += 4) {
                int ix[4];
#pragma unroll
                for (int q = 0; q < 4; ++q) ix[q] = bp[j + q];
                float a[4];
#pragma unroll
                for (int q = 0; q < 4; ++q) a[q] = bf2f(ht[(size_t)ix[q] * D + lane]);
                acc += (a[0] + a[1]) + (a[2] + a[3]);
            }
            for (; j < dg; ++j) acc += bf2f(ht[(size_t)bp[j] * D + lane]);
        }
        LA[(w4 + nn) * 66 + lane] = acc;
    }
    __syncthreads();
    {   // exact overflow drain (novf==0 in practice: one scalar load + barrier)
        int nv = novf[0];
        if (nv > 0) {
            for (int o = (t >> 6); o < nv; o += 4) {
                int dst = ovf[2 * o];
                if (dst >= n0 && dst < n0 + 16) {
                    int src = ovf[2 * o + 1];
                    atomicAdd(&LA[(dst - n0) * 66 + lane], bf2f(ht[(size_t)src * D + lane]));
                }
            }
        }
    }
    __syncthreads();

    // gates: lane = channel c; k-major weight rows (proven round-12)
    float ra[4], za[4], ia[4], ha[4];
    {
        float br = B[lane] + B[192 + lane];
        float bz = B[64 + lane] + B[256 + lane];
        float bi = B[128 + lane];
        float bh = B[320 + lane];
#pragma unroll
        for (int nn = 0; nn < 4; ++nn) { ra[nn] = br; za[nn] = bz; ia[nn] = bi; ha[nn] = bh; }
    }
#pragma unroll 2
    for (int kk = 0; kk < 32; ++kk) {
        int k0 = 2 * kk;
        float w0a = WC[k0 * 192 + lane];
        float w1a = WC[k0 * 192 + 64 + lane];
        float w2a = WC[k0 * 192 + 128 + lane];
        float w0b = WC[(k0 + 1) * 192 + lane];
        float w1b = WC[(k0 + 1) * 192 + 64 + lane];
        float w2b = WC[(k0 + 1) * 192 + 128 + lane];
        float v0a = WTh[k0 * 192 + lane];
        float v1a = WTh[k0 * 192 + 64 + lane];
        float v2a = WTh[k0 * 192 + 128 + lane];
        float v0b = WTh[(k0 + 1) * 192 + lane];
        float v1b = WTh[(k0 + 1) * 192 + 64 + lane];
        float v2b = WTh[(k0 + 1) * 192 + 128 + lane];
#pragma unroll
        for (int nn = 0; nn < 4; ++nn) {
            int rr = w4 + nn;
            float2 a = *(const float2*)&LA[rr * 66 + k0];
            float2 hh = *(const float2*)&LH[rr * 66 + k0];
            ra[nn] = fmaf(a.x, w0a, fmaf(hh.x, v0a, ra[nn]));
            ra[nn] = fmaf(a.y, w0b, fmaf(hh.y, v0b, ra[nn]));
            za[nn] = fmaf(a.x, w1a, fmaf(hh.x, v1a, za[nn]));
            za[nn] = fmaf(a.y, w1b, fmaf(hh.y, v1b, za[nn]));
            ia[nn] = fmaf(a.x, w2a, ia[nn]);
            ia[nn] = fmaf(a.y, w2b, ia[nn]);
            ha[nn] = fmaf(hh.x, v2a, ha[nn]);
            ha[nn] = fmaf(hh.y, v2b, ha[nn]);
        }
    }
#pragma unroll
    for (int nn = 0; nn < 4; ++nn) {
        int n = n0 + w4 + nn;
        float r = 1.f / (1.f + __expf(-ra[nn]));
        float z = 1.f / (1.f + __expf(-za[nn]));
        float nx = ia[nn] + r * ha[nn];
        float tnh = 1.f - 2.f / (1.f + __expf(2.f * nx));  // tanh, overflow-safe
        float hn = (1.f - z) * tnh + z * LH[(w4 + nn) * 66 + lane];
        if (n < N) {
            size_t idx = (size_t)n * D + lane;
            if (houtb) houtb[idx] = __bfloat16_as_ushort(__float2bfloat16(hn));
            else if (flags[0]) ((float*)dout)[idx] = hn;
            else ((bf16*)dout)[idx] = __float2bfloat16(hn);
        }
    }
}

extern "C" void kernel_launch(void* const* d_in, const int* in_sizes, int n_in,
                              void* d_out, int out_size, void* d_ws, size_t ws_size,
                              hipStream_t stream) {
    const void* x   = d_in[0];
    const int*  ei  = (const int*)d_in[1];
    const void* Wnt = d_in[4];
    const void* bnt = d_in[5];
    const void* Wt  = d_in[6];   // [3,64,64]
    const void* Wih = d_in[7];   // [192,64]
    const void* Whh = d_in[8];
    const void* bih = d_in[9];
    const void* bhh = d_in[10];

    int N = in_sizes[0] / 6;
    int E = in_sizes[1] / 2;
    int ND = N * D;

    // Workspace (~26 MB, within proven 38.4 MB):
    // flags | htA | htB | cnt(N) | novf(1) | ss16(N*64 u16) | ovf(2E int) | WCT | WTh | B
    int* flags = (int*)d_ws;
    u16* htA = (u16*)((char*)d_ws + 256);
    u16* htB = htA + ND;
    int* cnt  = (int*)(htB + ND);
    int* novf = cnt + N;
    u16* ss16 = (u16*)(novf + 1);
    int* ovf  = (int*)(ss16 + (size_t)N * 64);
    float* WCT = (float*)(ovf + 2 * (size_t)E);  // 36864
    float* WTh = WCT + N_WCT;                    // 12288
    float* B   = WTh + N_WTH;                    // 384

    int NT_BLK = (ND + 255) / 256;
    int WC_BLK = (N_WCT + N_WTH + N_B + 255) / 256;
    int FI_BLK = (E + 255) / 256;

    hipMemsetAsync(cnt, 0, (size_t)(N + 1) * sizeof(int), stream);
    detect_kernel<<<1, 256, 0, stream>>>(x, ei, flags);
    prep_all<<<NT_BLK + WC_BLK + FI_BLK, 256, 0, stream>>>(flags, x, Wnt, bnt, Wt, Wih, Whh,
                                                           bih, bhh, htA, WCT, WTh, B,
                                                           ei, cnt, ss16, novf, ovf,
                                                           E, N, NT_BLK, WC_BLK);

    u16* hcur = htA;
    u16* hnxt = htB;
    for (int layer = 0; layer < 3; ++layer) {
        bool last = (layer == 2);
        layer_fused<<<(N + 15) / 16, 256, 0, stream>>>(flags, hcur, cnt, ss16, novf, ovf,
                                                       WCT + layer * 12288, WTh, B,
                                                       last ? nullptr : hnxt,
                                                       last ? d_out : nullptr, N);
        u16* t = hcur; hcur = hnxt; hnxt = t;
    }
}